// Round 1
// baseline (381.156 us; speedup 1.0000x reference)
//
#include <hip/hip_runtime.h>

// Problem constants (from reference): D=1024, K=8, N=8192
#define DD 1024
#define KK 8
#define NN 8192

// Kernel 1: gather the diagonal of W.
// w_diag[m*D + i] = W[i*(K*D) + m*D + i]
__global__ __launch_bounds__(256) void gather_wdiag_kernel(
    const float* __restrict__ W, float* __restrict__ wd) {
    int idx = blockIdx.x * 256 + threadIdx.x;  // 0 .. K*D-1
    if (idx < KK * DD) {
        int m = idx / DD;
        int i = idx - m * DD;
        wd[idx] = W[(size_t)i * (KK * DD) + m * DD + i];
    }
}

// Kernel 2: streaming fused "diagonal grouped matvec".
// out[n, i] = b[i] + sum_m wd[m*D+i] * h_r[n, m*D+i]
// One float4 (4 consecutive i) per thread per row-iteration.
// Block = 256 threads covers D/4 = 256 float4 columns of one row.
// Grid-stride over rows: 2048 blocks (256 CU x 8).
__global__ __launch_bounds__(256) void impute_diag_kernel(
    const float* __restrict__ h_r,
    const float* __restrict__ wd,
    const float* __restrict__ b,
    float* __restrict__ out) {
    const int c = threadIdx.x;  // float4 column index, 0..255

    // b and wd are tiny and L2-resident; load per-thread constants once.
    const float4 bv = reinterpret_cast<const float4*>(b)[c];
    float4 w[KK];
#pragma unroll
    for (int m = 0; m < KK; ++m) {
        w[m] = reinterpret_cast<const float4*>(wd)[m * (DD / 4) + c];
    }

    for (int n = blockIdx.x; n < NN; n += gridDim.x) {
        const float4* h4 =
            reinterpret_cast<const float4*>(h_r + (size_t)n * (KK * DD));
        float4 acc = bv;
        float4 h[KK];
        // Issue all 8 loads first (MLP), then FMA.
#pragma unroll
        for (int m = 0; m < KK; ++m) {
            h[m] = h4[m * (DD / 4) + c];
        }
#pragma unroll
        for (int m = 0; m < KK; ++m) {
            acc.x += h[m].x * w[m].x;
            acc.y += h[m].y * w[m].y;
            acc.z += h[m].z * w[m].z;
            acc.w += h[m].w * w[m].w;
        }
        reinterpret_cast<float4*>(out)[(size_t)n * (DD / 4) + c] = acc;
    }
}

extern "C" void kernel_launch(void* const* d_in, const int* in_sizes, int n_in,
                              void* d_out, int out_size, void* d_ws, size_t ws_size,
                              hipStream_t stream) {
    const float* h_r = (const float*)d_in[0];  // (N, K*D)
    const float* W   = (const float*)d_in[1];  // (D, K*D)
    const float* b   = (const float*)d_in[2];  // (D,)
    float* out = (float*)d_out;                // (N, D)
    float* wd  = (float*)d_ws;                 // K*D floats = 32 KiB scratch

    // Gather diagonal: K*D = 8192 elements -> 32 blocks.
    gather_wdiag_kernel<<<(KK * DD + 255) / 256, 256, 0, stream>>>(W, wd);

    // Main streaming kernel: 2048 blocks x 256 threads, grid-stride rows.
    impute_diag_kernel<<<2048, 256, 0, stream>>>(h_r, wd, b, out);
}

// Round 3
// 361.814 us; speedup vs baseline: 1.0535x; 1.0535x over previous
//
#include <hip/hip_runtime.h>

// Problem constants (from reference): D=1024, K=8, N=8192
#define DD 1024
#define KK 8
#define NN 8192

// Native clang vector type — __builtin_nontemporal_load/store require a
// scalar/pointer/vector type, not HIP_vector_type<float,4>.
typedef float f32x4 __attribute__((ext_vector_type(4)));

// Kernel 1: gather the diagonal of W (one-shot, 8192 threads).
// w_diag[m*D + i] = W[i*(K*D) + m*D + i]
__global__ __launch_bounds__(256) void gather_wdiag_kernel(
    const float* __restrict__ W, float* __restrict__ wd) {
    int idx = blockIdx.x * 256 + threadIdx.x;  // 0 .. K*D-1
    if (idx < KK * DD) {
        int m = idx >> 10;          // idx / DD
        int i = idx & (DD - 1);     // idx % DD
        wd[idx] = W[(size_t)i * (KK * DD) + m * DD + i];
    }
}

// Kernel 2: streaming fused "diagonal grouped matvec".
// out[n, i] = b[i] + sum_m wd[m*D+i] * h_r[n, m*D+i]
// One f32x4 (4 consecutive i) per thread per row-iteration; a 64-lane wave
// reads 1 KB contiguous segments -> fully coalesced. h_r is streamed once
// (256 MB >> L2) and out written once: non-temporal hints keep the caches
// clean and avoid write-allocate overhead.
__global__ __launch_bounds__(256) void impute_diag_kernel(
    const float* __restrict__ h_r,
    const float* __restrict__ wd,
    const float* __restrict__ b,
    float* __restrict__ out) {
    const int c = threadIdx.x;  // f32x4 column index, 0..255

    // b and wd are tiny (4 KB / 32 KB) and L2-resident; hoist per-thread
    // constants out of the row loop (amortized over NN/gridDim rows).
    const f32x4 bv = reinterpret_cast<const f32x4*>(b)[c];
    f32x4 w[KK];
#pragma unroll
    for (int m = 0; m < KK; ++m) {
        w[m] = reinterpret_cast<const f32x4*>(wd)[m * (DD / 4) + c];
    }

    for (int n = blockIdx.x; n < NN; n += gridDim.x) {
        const f32x4* h4 =
            reinterpret_cast<const f32x4*>(h_r + (size_t)n * (KK * DD));
        f32x4 h[KK];
        // Issue all 8 non-temporal loads first (MLP), then FMA.
#pragma unroll
        for (int m = 0; m < KK; ++m) {
            h[m] = __builtin_nontemporal_load(&h4[m * (DD / 4) + c]);
        }
        f32x4 acc = bv;
#pragma unroll
        for (int m = 0; m < KK; ++m) {
            acc.x = fmaf(h[m].x, w[m].x, acc.x);
            acc.y = fmaf(h[m].y, w[m].y, acc.y);
            acc.z = fmaf(h[m].z, w[m].z, acc.z);
            acc.w = fmaf(h[m].w, w[m].w, acc.w);
        }
        __builtin_nontemporal_store(
            acc, &reinterpret_cast<f32x4*>(out)[(size_t)n * (DD / 4) + c]);
    }
}

extern "C" void kernel_launch(void* const* d_in, const int* in_sizes, int n_in,
                              void* d_out, int out_size, void* d_ws, size_t ws_size,
                              hipStream_t stream) {
    const float* h_r = (const float*)d_in[0];  // (N, K*D)
    const float* W   = (const float*)d_in[1];  // (D, K*D)
    const float* b   = (const float*)d_in[2];  // (D,)
    float* out = (float*)d_out;                // (N, D)
    float* wd  = (float*)d_ws;                 // K*D floats = 32 KiB scratch

    // Gather diagonal: K*D = 8192 elements -> 32 blocks (~3 us, scattered
    // but one-shot; fusing this into the main kernel would pay the scatter
    // per-block = tens of us of L1 transactions).
    gather_wdiag_kernel<<<(KK * DD + 255) / 256, 256, 0, stream>>>(W, wd);

    // Main streaming kernel: 2048 blocks x 256 threads (8 blocks/CU, all
    // resident), grid-stride over 4 rows each.
    impute_diag_kernel<<<2048, 256, 0, stream>>>(h_r, wd, b, out);
}